// Round 12
// baseline (762.530 us; speedup 1.0000x reference)
//
#include <hip/hip_runtime.h>
#include <math.h>

// Problem dims: B=16, C=256, H=W=128
#define BATCHES       16
#define HW            (128 * 128)
#define VEC_PER_BATCH (1 << 20)            // float4 per (input,batch)
#define T             256
#define NPROD         512                  // producer blocks
#define NCONS         512                  // consumer blocks
#define VEC_PER_BLK   (VEC_PER_BATCH / NPROD)  // 2048 float4 per input per block
#define KP            (VEC_PER_BLK / T)    // 8 float4 per thread per input
#define NMID          8
#define BLKS_PER_MID  (NPROD / NMID)       // 64
#define SPIN_CAP      (1 << 26)            // ~1s worst case; never hit if sync OK

// ws layout (bytes):
//   part[16][3][512] floats @ 0       (98304 B)
//   sync region @ 102400 (memset each call):
//     mid [16][8] : 64B lines  (8192 B)
//     root[16]    : 64B lines  (1024 B)
#define SYNC_OFF_B   102400
#define MID_OFF_B    102400
#define ROOT_OFF_B   (102400 + 8192)
#define SYNC_BYTES   (8192 + 1024)

typedef float f32x4 __attribute__((ext_vector_type(4)));

#define LD_RLX(p)   __hip_atomic_load((p), __ATOMIC_RELAXED, __HIP_MEMORY_SCOPE_AGENT)
#define LD_ACQ(p)   __hip_atomic_load((p), __ATOMIC_ACQUIRE, __HIP_MEMORY_SCOPE_AGENT)
#define ST_RLX(p,v) __hip_atomic_store((p), (v), __ATOMIC_RELAXED, __HIP_MEMORY_SCOPE_AGENT)
#define FAA_AR(p,v) __hip_atomic_fetch_add((p), (v), __ATOMIC_ACQ_REL, __HIP_MEMORY_SCOPE_AGENT)

__global__ __launch_bounds__(T, 4) void fusion_pc_kernel(
    const f32x4* __restrict__ gray,
    const f32x4* __restrict__ green,
    const f32x4* __restrict__ rgb,
    const float* __restrict__ conv_w,
    const float* __restrict__ conv_b,
    float* __restrict__ part,           // [16][3][NPROD]
    unsigned int* __restrict__ mid,     // [16][8] stride 16 uints
    unsigned int* __restrict__ root,    // [16]    stride 16 uints
    f32x4* __restrict__ out)
{
    const int blk  = (int)blockIdx.x;
    const int t    = (int)threadIdx.x;
    const int lane = t & 63;
    const int wid  = t >> 6;

    __shared__ float red[3][T / 64];

    if (blk < NPROD) {
        // ------------- PRODUCER: stream read-once + reduce, never waits ------
        const float w = conv_w[blk >> 1];   // block = half a channel
        #pragma unroll 1
        for (int p = 0; p < BATCHES; ++p) {
            const size_t base = (size_t)p * VEC_PER_BATCH
                              + (size_t)blk * VEC_PER_BLK + (size_t)t;
            float sg = 0.f, sn = 0.f, sr = 0.f;
            {
                f32x4 v[KP];
                #pragma unroll
                for (int k = 0; k < KP; ++k) v[k] = gray[base + (size_t)(k * T)];
                #pragma unroll
                for (int k = 0; k < KP; ++k) sg += (v[k].x + v[k].y) + (v[k].z + v[k].w);
                #pragma unroll
                for (int k = 0; k < KP; ++k) v[k] = green[base + (size_t)(k * T)];
                #pragma unroll
                for (int k = 0; k < KP; ++k) sn += (v[k].x + v[k].y) + (v[k].z + v[k].w);
                #pragma unroll
                for (int k = 0; k < KP; ++k) v[k] = rgb[base + (size_t)(k * T)];
                #pragma unroll
                for (int k = 0; k < KP; ++k) sr += (v[k].x + v[k].y) + (v[k].z + v[k].w);
            }
            #pragma unroll
            for (int off = 32; off > 0; off >>= 1) {
                sg += __shfl_down(sg, off, 64);
                sn += __shfl_down(sn, off, 64);
                sr += __shfl_down(sr, off, 64);
            }
            if (lane == 0) { red[0][wid] = sg; red[1][wid] = sn; red[2][wid] = sr; }
            __syncthreads();
            if (t == 0) {
                float* P = part + (size_t)p * 3 * NPROD;
                ST_RLX(&P[0 * NPROD + blk], ((red[0][0] + red[0][1]) + (red[0][2] + red[0][3])) * w);
                ST_RLX(&P[1 * NPROD + blk], ((red[1][0] + red[1][1]) + (red[1][2] + red[1][3])) * w);
                ST_RLX(&P[2 * NPROD + blk], ((red[2][0] + red[2][1]) + (red[2][2] + red[2][3])) * w);
                unsigned prev = FAA_AR(&mid[(p * NMID + (blk / BLKS_PER_MID)) * 16], 1u);
                if (prev == BLKS_PER_MID - 1)
                    FAA_AR(&root[p * 16], 1u);
            }
            __syncthreads();   // red[] reused next phase
        }
    } else {
        // --------- CONSUMER: wait on PRODUCER-only root, self-fold, apply ----
        // No consumer->consumer dependency: deadlock-immune by construction.
        const int c = blk - NPROD;
        const float bias = conv_b[0];
        #pragma unroll 1
        for (int p = 0; p < BATCHES; ++p) {
            if (t == 0) {
                int it = 0;
                while (LD_RLX(&root[p * 16]) < NMID && ++it < SPIN_CAP)
                    __builtin_amdgcn_s_sleep(1);
                (void)LD_ACQ(&root[p * 16]);
            }
            __syncthreads();

            // fold all 512x3 partials locally (L2-hot, ~6KB)
            #pragma unroll
            for (int i = 0; i < 3; ++i) {
                const float* Pi = part + ((size_t)p * 3 + i) * NPROD;
                float v = LD_RLX(&Pi[t]) + LD_RLX(&Pi[t + 256]);
                #pragma unroll
                for (int off = 32; off > 0; off >>= 1) v += __shfl_down(v, off, 64);
                if (lane == 0) red[i][wid] = v;
            }
            __syncthreads();
            float a0, a1, a2;
            {
                float t0 = (red[0][0] + red[0][1]) + (red[0][2] + red[0][3]);
                float t1 = (red[1][0] + red[1][1]) + (red[1][2] + red[1][3]);
                float t2 = (red[2][0] + red[2][1]) + (red[2][2] + red[2][3]);
                a0 = 1.0f / (1.0f + expf(-(t0 * (1.0f / (float)HW) + bias)));
                a1 = 1.0f / (1.0f + expf(-(t1 * (1.0f / (float)HW) + bias)));
                a2 = 1.0f / (1.0f + expf(-(t2 * (1.0f / (float)HW) + bias)));
            }

            // apply slice c of batch p (reads L3-resident data behind producers)
            const size_t base = (size_t)p * VEC_PER_BATCH
                              + (size_t)c * VEC_PER_BLK + (size_t)t;
            #pragma unroll
            for (int k = 0; k < KP; ++k) {
                f32x4 g = gray [base + (size_t)(k * T)];
                f32x4 n = green[base + (size_t)(k * T)];
                f32x4 r = rgb  [base + (size_t)(k * T)];
                f32x4 o = g * a0 + (n * a1 + r * a2) * 10.0f;
                __builtin_nontemporal_store(o, &out[base + (size_t)(k * T)]);
            }
            __syncthreads();   // red[] reused next phase
        }
    }
}

extern "C" void kernel_launch(void* const* d_in, const int* in_sizes, int n_in,
                              void* d_out, int out_size, void* d_ws, size_t ws_size,
                              hipStream_t stream) {
    const f32x4* gray   = (const f32x4*)d_in[0];
    const f32x4* green  = (const f32x4*)d_in[1];
    const f32x4* rgb    = (const f32x4*)d_in[2];
    const float* conv_w = (const float*)d_in[3];
    const float* conv_b = (const float*)d_in[4];
    f32x4* out = (f32x4*)d_out;

    float*        part = (float*)d_ws;
    unsigned int* mid  = (unsigned int*)((char*)d_ws + MID_OFF_B);
    unsigned int* root = (unsigned int*)((char*)d_ws + ROOT_OFF_B);

    hipMemsetAsync((char*)d_ws + SYNC_OFF_B, 0, SYNC_BYTES, stream);

    fusion_pc_kernel<<<NPROD + NCONS, T, 0, stream>>>(
        gray, green, rgb, conv_w, conv_b, part, mid, root, out);
}

// Round 13
// 313.128 us; speedup vs baseline: 2.4352x; 2.4352x over previous
//
#include <hip/hip_runtime.h>
#include <math.h>

// Problem dims (hardcoded from reference):
//   B=16, C=256, H=W=128
#define BATCHES      16
#define CHANNELS     256
#define HW           (128 * 128)                 // 16384 floats per channel
#define PER_BATCH    (CHANNELS * HW)             // 4,194,304 floats per (input,batch)
#define VEC_PER_BATCH (PER_BATCH / 4)            // 1,048,576 float4 (2^20)
#define RTHREADS      256

// Reduce geometry (apply-like shape): each block = 256 threads x 4 float4
//   = 1024 float4 = 4096 floats = exactly ONE channel of one (input,batch).
// Blocks per input = 2^24 / 1024 = 16384; total = 3*16384 = 49152.
#define K1_BLOCKS     49152
#define VECS_PER_K1   1024                        // float4 per block
#define PARTS_PER_ROW 1024                        // partials per (which,batch)

// ws layout (floats): [0 .. 49151] partials, [49152 .. 49199] att scalars
#define PARTIALS_OFF 0
#define ATT_OFF      K1_BLOCKS

typedef float f32x4 __attribute__((ext_vector_type(4)));

// ---------------------------------------------------------------------------
// Kernel 1: per-block weighted partial sums, apply-like memory shape.
// 4 independent float4 loads per thread, tiny VGPR, 49152 blocks.
// ---------------------------------------------------------------------------
__global__ __launch_bounds__(RTHREADS) void fusion_reduce_kernel(
    const float* __restrict__ gray,
    const float* __restrict__ green,
    const float* __restrict__ rgb,
    const float* __restrict__ conv_w,
    float* __restrict__ partials)
{
    int g     = blockIdx.x;
    int which = g >> 14;                      // 16384 blocks per input
    int inner = g & 16383;
    size_t base = (size_t)inner * VECS_PER_K1;  // float4 index within input

    const float* x = (which == 0) ? gray : (which == 1) ? green : rgb;
    const float4* xv = reinterpret_cast<const float4*>(x) + base;

    // whole block lies in one channel: ch = (base>>12) & 255 (wave-uniform)
    float w = conv_w[(int)((base >> 12) & (CHANNELS - 1))];

    float4 d0 = xv[threadIdx.x + 0 * RTHREADS];
    float4 d1 = xv[threadIdx.x + 1 * RTHREADS];
    float4 d2 = xv[threadIdx.x + 2 * RTHREADS];
    float4 d3 = xv[threadIdx.x + 3 * RTHREADS];
    float sum = ((d0.x + d0.y) + (d0.z + d0.w))
              + ((d1.x + d1.y) + (d1.z + d1.w))
              + ((d2.x + d2.y) + (d2.z + d2.w))
              + ((d3.x + d3.y) + (d3.z + d3.w));

    // wave64 tree reduce
    #pragma unroll
    for (int off = 32; off > 0; off >>= 1) sum += __shfl_down(sum, off, 64);

    __shared__ float s4[RTHREADS / 64];
    int wid = threadIdx.x >> 6;
    if ((threadIdx.x & 63) == 0) s4[wid] = sum;
    __syncthreads();
    if (threadIdx.x == 0) {
        partials[g] = ((s4[0] + s4[1]) + (s4[2] + s4[3])) * w;
    }
}

// ---------------------------------------------------------------------------
// Kernel 2: fold 1024 partials per (which,batch) -> sigmoid attention scalar.
// grid.x = 48, block = 256; 4 partials per thread.
// ---------------------------------------------------------------------------
__global__ __launch_bounds__(RTHREADS) void fusion_att_kernel(
    const float* __restrict__ partials,
    const float* __restrict__ conv_b,
    float* __restrict__ att)
{
    int row = blockIdx.x;                  // which*16 + batch
    const float* p = partials + (size_t)row * PARTS_PER_ROW;
    float v = p[threadIdx.x + 0 * RTHREADS] + p[threadIdx.x + 1 * RTHREADS]
            + p[threadIdx.x + 2 * RTHREADS] + p[threadIdx.x + 3 * RTHREADS];

    #pragma unroll
    for (int off = 32; off > 0; off >>= 1) v += __shfl_down(v, off, 64);

    __shared__ float s4[RTHREADS / 64];
    int wid = threadIdx.x >> 6;
    if ((threadIdx.x & 63) == 0) s4[wid] = v;
    __syncthreads();
    if (threadIdx.x == 0) {
        float total = (s4[0] + s4[1]) + (s4[2] + s4[3]);
        float logit = total * (1.0f / (float)HW) + conv_b[0];
        att[row] = 1.0f / (1.0f + expf(-logit));
    }
}

// ---------------------------------------------------------------------------
// Kernel 3: apply attention and fuse.
// out = gray*a_g + 10*(green*a_gr + rgb*a_r), float4 granularity.
// Non-temporal store: output is never re-read; keep inputs resident in L3.
// ---------------------------------------------------------------------------
__global__ __launch_bounds__(RTHREADS) void fusion_apply_kernel(
    const float4* __restrict__ gray,
    const float4* __restrict__ green,
    const float4* __restrict__ rgb,
    const float* __restrict__ att,
    float4* __restrict__ out)
{
    size_t i = (size_t)blockIdx.x * RTHREADS + threadIdx.x;
    int b = (int)(i >> 20);                // VEC_PER_BATCH = 2^20
    float ag  = att[b];
    float agr = att[BATCHES + b];
    float ar  = att[2 * BATCHES + b];

    float4 dg = gray[i], dn = green[i], dr = rgb[i];
    f32x4 o;
    o.x = dg.x * ag + 10.0f * (dn.x * agr + dr.x * ar);
    o.y = dg.y * ag + 10.0f * (dn.y * agr + dr.y * ar);
    o.z = dg.z * ag + 10.0f * (dn.z * agr + dr.z * ar);
    o.w = dg.w * ag + 10.0f * (dn.w * agr + dr.w * ar);
    __builtin_nontemporal_store(o, reinterpret_cast<f32x4*>(&out[i]));
}

extern "C" void kernel_launch(void* const* d_in, const int* in_sizes, int n_in,
                              void* d_out, int out_size, void* d_ws, size_t ws_size,
                              hipStream_t stream) {
    const float* gray   = (const float*)d_in[0];
    const float* green  = (const float*)d_in[1];
    const float* rgb    = (const float*)d_in[2];
    const float* conv_w = (const float*)d_in[3];
    const float* conv_b = (const float*)d_in[4];
    float* out = (float*)d_out;
    float* ws  = (float*)d_ws;

    float* partials = ws + PARTIALS_OFF;   // 49152 floats (192 KB)
    float* att      = ws + ATT_OFF;        // 48 floats

    // Pass 1: weighted partial sums (reads all 3 inputs once)
    fusion_reduce_kernel<<<K1_BLOCKS, RTHREADS, 0, stream>>>(
        gray, green, rgb, conv_w, partials);

    // Pass 2: fold partials + sigmoid (48 scalars)
    fusion_att_kernel<<<3 * BATCHES, RTHREADS, 0, stream>>>(
        partials, conv_b, att);

    // Pass 3: apply + fuse (reads all 3 inputs again, writes output)
    int total_vec = BATCHES * VEC_PER_BATCH;     // 16,777,216
    fusion_apply_kernel<<<total_vec / RTHREADS, RTHREADS, 0, stream>>>(
        (const float4*)gray, (const float4*)green, (const float4*)rgb,
        att, (float4*)out);
}